// Round 11
// baseline (168.071 us; speedup 1.0000x reference)
//
#include <hip/hip_runtime.h>
#include <cstdint>

// Problem constants: B=2, L=2048, D=1024, H=16, DK=64
#define SEQ     2048
#define DMODEL  1024
#define NHEAD   16
#define DKH     64
#define NTOK    4096      // B*L
#define LDQKV   3072      // qkv buffer row stride (q|k|v)

typedef __bf16 bf16x8 __attribute__((ext_vector_type(8)));
typedef __bf16 bf16x4 __attribute__((ext_vector_type(4)));
typedef float  f32x4  __attribute__((ext_vector_type(4)));

#define MFMA_BF16(a, b, c) __builtin_amdgcn_mfma_f32_16x16x32_bf16((a), (b), (c), 0, 0, 0)

// 0.125 * log2(e): folded into wq/bq at pack time. Softmax shift dropped
// entirely — exp2(s) scales O and l identically, cancels in O/l.
#define C2F 0.18033688f

__device__ inline float fast_exp2(float x) {
#if __has_builtin(__builtin_amdgcn_exp2f)
  return __builtin_amdgcn_exp2f(x);
#else
  return __expf(x * 0.69314718056f);
#endif
}

// async global->LDS copy, 16B per lane; LDS dest is wave-uniform base + lane*16
__device__ inline void async_copy16(const void* g, void* l) {
  __builtin_amdgcn_global_load_lds(
      reinterpret_cast<const __attribute__((address_space(1))) void*>(
          reinterpret_cast<uintptr_t>(g)),
      reinterpret_cast<__attribute__((address_space(3))) void*>(
          reinterpret_cast<uintptr_t>(l)),
      16, 0, 0);
}

__device__ inline bf16x4 cvt4(float4 v) {
  bf16x4 r;
  r[0] = (__bf16)v.x; r[1] = (__bf16)v.y; r[2] = (__bf16)v.z; r[3] = (__bf16)v.w;
  return r;
}

// ---------------- pack: fp32 -> bf16 casts + weight/bias concat ----------------
__global__ __launch_bounds__(256) void pack_kernel(
    const float4* __restrict__ x,
    const float4* __restrict__ wq, const float4* __restrict__ wk,
    const float4* __restrict__ wv, const float4* __restrict__ wo,
    const float4* __restrict__ bq, const float4* __restrict__ bk,
    const float4* __restrict__ bv,
    bf16x4* __restrict__ xb, bf16x4* __restrict__ wqkv,
    bf16x4* __restrict__ wob, float4* __restrict__ bcat)
{
  const int NX = NTOK * DMODEL / 4;       // 1048576 float4 groups of x
  const int NW = DMODEL * DMODEL / 4;     // 262144 per weight
  const int TOT = NX + 4 * NW + 3 * (DMODEL / 4);
  for (int g = blockIdx.x * 256 + threadIdx.x; g < TOT; g += gridDim.x * 256) {
    if (g < NX) {
      xb[g] = cvt4(x[g]);
    } else if (g < NX + 3 * NW) {
      int g2 = g - NX;
      const float4* s = (g2 < NW) ? wq : (g2 < 2 * NW ? wk : wv);
      float4 v = s[g2 & (NW - 1)];
      if (g2 < NW) { v.x *= C2F; v.y *= C2F; v.z *= C2F; v.w *= C2F; }
      wqkv[g2] = cvt4(v);
    } else if (g < NX + 4 * NW) {
      int g3 = g - NX - 3 * NW;
      wob[g3] = cvt4(wo[g3]);
    } else {
      int g4 = g - NX - 4 * NW;
      const float4* s = (g4 < 256) ? bq : (g4 < 512 ? bk : bv);
      float4 v = s[g4 & 255];
      if (g4 < 256) { v.x *= C2F; v.y *= C2F; v.z *= C2F; v.w *= C2F; }
      bcat[g4] = v;
    }
  }
}

// ---------------- QKV GEMM, 256x192 tile, BK=64, 8 waves, phase-split ---------
// (r7 verified structure: 256 blocks = exactly 1/CU, XCD-chunked.)
// r11: V-column outputs (col >= 2048) are written TRANSPOSED directly to vt
// (vtrans kernel deleted). Branch is wave-uniform (16-aligned col groups,
// 2048 is 16-aligned); each lane's 4 acc values are 4 consecutive tokens ->
// one aligned bf16x4 store; per-instruction fragmentation (16 rows x 32B)
// matches the old scalar V-column writes, so epilogue cost is a wash while
// 16MB of vtrans traffic + a dispatch disappear. Blocks never span the
// batch boundary (m0 256-aligned, 2048%256==0) -> b = m0>>11 block-uniform.
__global__ __launch_bounds__(512, 2) void gemm_qkv_256x192(
    const __bf16* __restrict__ A,    // xb  [4096][1024]
    const __bf16* __restrict__ W,    // wqkv [3072][1024]
    const float* __restrict__ bias,  // bcat [3072]
    __bf16* __restrict__ C,          // qkv [4096][3072] (q|k slices used)
    __bf16* __restrict__ vt)         // [32*64][2048] transposed V
{
  constexpr int K = 1024;
  __shared__ __bf16 sA[2][256 * 64];  // 32KB each
  __shared__ __bf16 sB[2][192 * 64];  // 24KB each
  const int tid  = threadIdx.x;
  const int wave = tid >> 6, lane = tid & 63;
  const int quad = lane >> 4, l16 = lane & 15;
  const int wm = wave >> 2, wn = wave & 3;     // 2 x 4 wave grid
  const int swl = l16 & 7;
  const int bid = blockIdx.x;
  const int xcd = bid & 7, slot = bid >> 3;
  const int mt = (xcd >> 1) * 4 + (slot >> 3);   // 0..15
  const int nt = (xcd & 1) * 8 + (slot & 7);     // 0..15
  const size_t m0 = (size_t)mt * 256;
  const size_t n0 = (size_t)nt * 192;

  // staging bases: lane -> (row = chunk*8 + lane>>3, LDS granule lane&7,
  // source granule pre-swizzled by row&7)
  const int srow = lane >> 3;
  const int sgr  = (lane & 7) ^ srow;
  const __bf16* pA = A + (m0 + srow) * K + sgr * 8;
  const __bf16* pB = W + (n0 + srow) * K + sgr * 8;

  f32x4 acc[8][3];
  const f32x4 z = {0.f, 0.f, 0.f, 0.f};
#pragma unroll
  for (int i = 0; i < 8; ++i)
#pragma unroll
    for (int j = 0; j < 3; ++j) acc[i][j] = z;

#define STAGE_QKV(buf, k0)                                                    \
  {                                                                           \
    _Pragma("unroll")                                                         \
    for (int L = 0; L < 4; ++L) {          /* A: 32 chunks of 8 rows */       \
      const int c = L * 8 + wave;                                             \
      async_copy16(pA + (size_t)(c * 8) * K + (k0), &sA[buf][c * 512]);       \
    }                                                                         \
    _Pragma("unroll")                                                         \
    for (int L = 0; L < 3; ++L) {          /* B: 24 chunks of 8 rows */       \
      const int c = L * 8 + wave;                                             \
      async_copy16(pB + (size_t)(c * 8) * K + (k0), &sB[buf][c * 512]);       \
    }                                                                         \
  }

  int cur = 0;
  STAGE_QKV(0, 0);
  __syncthreads();                   // vmcnt(0) drain: tile 0 landed

  for (int t = 0; t < 16; ++t) {
    const __bf16* A_ = &sA[cur][0];
    const __bf16* B_ = &sB[cur][0];
    if (t + 1 < 16) STAGE_QKV(cur ^ 1, (t + 1) * 64);   // earliest issue

    bf16x8 af[4][2], bw[3][2];
    // ---- phase 1: B cols (all 3 j) + A rows 0..63 of wave; acc[0..3][*]
#pragma unroll
    for (int j = 0; j < 3; ++j) {
      const __bf16* r = B_ + (wn * 48 + j * 16 + l16) * 64;
      bw[j][0] = *(const bf16x8*)(r + ((quad ^ swl) * 8));
      bw[j][1] = *(const bf16x8*)(r + (((4 + quad) ^ swl) * 8));
    }
#pragma unroll
    for (int i = 0; i < 4; ++i) {
      const __bf16* r = A_ + (wm * 128 + i * 16 + l16) * 64;
      af[i][0] = *(const bf16x8*)(r + ((quad ^ swl) * 8));
      af[i][1] = *(const bf16x8*)(r + (((4 + quad) ^ swl) * 8));
    }
    __builtin_amdgcn_s_setprio(1);
#pragma unroll
    for (int i = 0; i < 4; ++i)
#pragma unroll
      for (int j = 0; j < 3; ++j) {
        acc[i][j] = MFMA_BF16(af[i][0], bw[j][0], acc[i][j]);
        acc[i][j] = MFMA_BF16(af[i][1], bw[j][1], acc[i][j]);
      }
    __builtin_amdgcn_s_setprio(0);
    __builtin_amdgcn_s_barrier();

    // ---- phase 2: A rows 64..127 (overwrite af); acc[4..7][*]; boundary
#pragma unroll
    for (int i = 0; i < 4; ++i) {
      const __bf16* r = A_ + (wm * 128 + 64 + i * 16 + l16) * 64;
      af[i][0] = *(const bf16x8*)(r + ((quad ^ swl) * 8));
      af[i][1] = *(const bf16x8*)(r + (((4 + quad) ^ swl) * 8));
    }
    __builtin_amdgcn_s_setprio(1);
#pragma unroll
    for (int i = 0; i < 4; ++i)
#pragma unroll
      for (int j = 0; j < 3; ++j) {
        acc[4 + i][j] = MFMA_BF16(af[i][0], bw[j][0], acc[4 + i][j]);
        acc[4 + i][j] = MFMA_BF16(af[i][1], bw[j][1], acc[4 + i][j]);
      }
    __builtin_amdgcn_s_setprio(0);
    asm volatile("s_waitcnt vmcnt(0)" ::: "memory");  // next tile landed
    __builtin_amdgcn_s_barrier();
    cur ^= 1;
  }
#undef STAGE_QKV

  float bi[3];
#pragma unroll
  for (int j = 0; j < 3; ++j) bi[j] = bias[n0 + wn * 48 + j * 16 + l16];

  const int bb = (int)(m0 >> 11);            // batch index (block-uniform)
  const int ltok0 = (int)(m0 & 2047) + wm * 128;

#pragma unroll
  for (int i = 0; i < 8; ++i)
#pragma unroll
    for (int j = 0; j < 3; ++j) {
      const int col = (int)n0 + wn * 48 + j * 16 + l16;
      if (col < 2048) {
        // Q|K slice: row-major qkv write (as before)
#pragma unroll
        for (int r = 0; r < 4; ++r) {
          size_t row = m0 + wm * 128 + i * 16 + quad * 4 + r;
          C[row * LDQKV + col] = (__bf16)(acc[i][j][r] + bi[j]);
        }
      } else {
        // V slice: transposed write straight to vt (4 consecutive tokens)
        bf16x4 v4;
#pragma unroll
        for (int r = 0; r < 4; ++r) v4[r] = (__bf16)(acc[i][j][r] + bi[j]);
        const size_t vrow = (size_t)(bb * 1024 + (col - 2048));
        const int ltok = ltok0 + i * 16 + quad * 4;
        *(bf16x4*)(vt + vrow * SEQ + ltok) = v4;
      }
    }
}

// ---------------- out-proj GEMM, 128x128 tile, BK=64, 8 waves -----------------
// (r8 verified: 256 blocks = exactly 1/CU, XCD-chunked. Frozen.)
__global__ __launch_bounds__(512, 2) void gemm_out_128(
    const __bf16* __restrict__ A,    // attn [4096][1024]
    const __bf16* __restrict__ W,    // wob  [1024][1024]
    const float* __restrict__ bias,  // bo   [1024]
    float* __restrict__ C)           // out  [4096][1024]
{
  constexpr int K = 1024;
  __shared__ __bf16 sA[2][128 * 64];  // 16KB each
  __shared__ __bf16 sB[2][128 * 64];
  const int tid  = threadIdx.x;
  const int wave = tid >> 6, lane = tid & 63;
  const int quad = lane >> 4, l16 = lane & 15;
  const int wm = wave >> 2, wn = wave & 3;     // 2 x 4 wave grid
  const int swl = l16 & 7;
  const int bid = blockIdx.x;
  const int xcd = bid & 7, slot = bid >> 3;    // slot 0..31
  const int mt = xcd * 4 + (slot >> 3);        // 0..31
  const int nt = slot & 7;                     // 0..7
  const size_t m0 = (size_t)mt * 128;
  const size_t n0 = (size_t)nt * 128;

  const int srow = lane >> 3;
  const int sgr  = (lane & 7) ^ srow;
  const __bf16* pA = A + (m0 + srow) * K + sgr * 8;
  const __bf16* pB = W + (n0 + srow) * K + sgr * 8;

  f32x4 acc[4][2];
  const f32x4 z = {0.f, 0.f, 0.f, 0.f};
#pragma unroll
  for (int i = 0; i < 4; ++i)
#pragma unroll
    for (int j = 0; j < 2; ++j) acc[i][j] = z;

#define STAGE_OUT(buf, k0)                                                    \
  {                                                                           \
    _Pragma("unroll")                                                         \
    for (int L = 0; L < 2; ++L) {          /* 16 chunks of 8 rows each */     \
      const int c = L * 8 + wave;                                             \
      async_copy16(pA + (size_t)(c * 8) * K + (k0), &sA[buf][c * 512]);       \
      async_copy16(pB + (size_t)(c * 8) * K + (k0), &sB[buf][c * 512]);       \
    }                                                                         \
  }

  int cur = 0;
  STAGE_OUT(0, 0);
  __syncthreads();                   // vmcnt(0) drain: tile 0 landed

  for (int t = 0; t < 16; ++t) {
    const __bf16* A_ = &sA[cur][0];
    const __bf16* B_ = &sB[cur][0];
    if (t + 1 < 16) STAGE_OUT(cur ^ 1, (t + 1) * 64);   // earliest issue

    bf16x8 af[4][2], bw[2][2];
#pragma unroll
    for (int j = 0; j < 2; ++j) {
      const __bf16* r = B_ + (wn * 32 + j * 16 + l16) * 64;
      bw[j][0] = *(const bf16x8*)(r + ((quad ^ swl) * 8));
      bw[j][1] = *(const bf16x8*)(r + (((4 + quad) ^ swl) * 8));
    }
#pragma unroll
    for (int i = 0; i < 4; ++i) {
      const __bf16* r = A_ + (wm * 64 + i * 16 + l16) * 64;
      af[i][0] = *(const bf16x8*)(r + ((quad ^ swl) * 8));
      af[i][1] = *(const bf16x8*)(r + (((4 + quad) ^ swl) * 8));
    }
    __builtin_amdgcn_s_setprio(1);
#pragma unroll
    for (int i = 0; i < 4; ++i)
#pragma unroll
      for (int j = 0; j < 2; ++j) {
        acc[i][j] = MFMA_BF16(af[i][0], bw[j][0], acc[i][j]);
        acc[i][j] = MFMA_BF16(af[i][1], bw[j][1], acc[i][j]);
      }
    __builtin_amdgcn_s_setprio(0);
    asm volatile("s_waitcnt vmcnt(0)" ::: "memory");  // next tile landed
    __builtin_amdgcn_s_barrier();    // all reads of cur done; nxt complete
    cur ^= 1;
  }
#undef STAGE_OUT

  float bi[2];
#pragma unroll
  for (int j = 0; j < 2; ++j) bi[j] = bias[n0 + wn * 32 + j * 16 + l16];

#pragma unroll
  for (int i = 0; i < 4; ++i)
#pragma unroll
    for (int j = 0; j < 2; ++j)
#pragma unroll
      for (int r = 0; r < 4; ++r) {
        size_t row = m0 + wm * 64 + i * 16 + quad * 4 + r;
        size_t col = n0 + wn * 32 + j * 16 + l16;
        C[row * DMODEL + col] = acc[i][j][r] + bi[j];
      }
}

// ---------------- MFMA flash attention (causal) -------------------------------
// (r10 verified: in-register P via pi-permuted K staging; bit-identical to
// the r3 pbuf path with the LDS round-trip deleted. Frozen.)
__global__ __launch_bounds__(256) void attn_kernel(
    const __bf16* __restrict__ qkv,   // [4096][3072]
    const __bf16* __restrict__ vt,    // [32*64][2048]
    __bf16* __restrict__ attn)        // [4096][1024]
{
  __shared__ __bf16 sK[2][64 * 64];   // [key pi-permuted][dk], granule-swizzled
  __shared__ __bf16 sV[2][64 * 64];   // [dk][key], granule-swizzled
  const int tid  = threadIdx.x;
  const int wave = tid >> 6, lane = tid & 63;
  const int quad = lane >> 4, l16 = lane & 15;
  const int id = blockIdx.x;
  const int u = (id >> 3) & 31, v = id & 7, w = id >> 8;
  const int bh = v * 4 + w;
  const int ue = u ^ ((w >> 1) << 3);         // temporal mix across the CU's 4 blocks
  const int qb = (w & 1) ? ue : 31 - ue;
  const int b = bh >> 4, h = bh & 15;
  const int q0 = qb * 64;
  const int qw = q0 + wave * 16;              // wave's first query row
  const size_t tokbase = (size_t)b * SEQ;

  // staging: lane l -> (LDS row = l>>3, swizzled granule (l&7)^(l>>3))
  const int srow = lane >> 3;
  const int sgr  = (lane & 7) ^ srow;
  // K source row for LDS row (wave*16 + instr*8 + srow) under pi:
  //   krow = (wave>>1)*32 + (wave&1)*4 + (lane>>5)*8 + ((lane>>3)&3)
  //   instr 0 -> +0 rows, instr 1 -> +16 rows
  const int krow = (wave >> 1) * 32 + (wave & 1) * 4 + (lane >> 5) * 8 + (srow & 3);
  const __bf16* pKsrc = qkv + (tokbase + krow) * LDQKV + 1024 + h * DKH + sgr * 8;
  const __bf16* pVsrc = vt + ((size_t)bh * DKH + wave * 16 + srow) * SEQ + sgr * 8;
  const int lo = wave * 16 * 64;              // wave's slab within buffer

  bf16x8 qf[2];
#pragma unroll
  for (int s = 0; s < 2; ++s)
    qf[s] = *(const bf16x8*)(qkv + (tokbase + qw + l16) * LDQKV + h * DKH + s * 32 + quad * 8);

  bf16x8 ones;
#pragma unroll
  for (int i = 0; i < 8; ++i) ones[i] = (__bf16)1.0f;

  f32x4 o[4], lacc;
  const f32x4 z = {0.f, 0.f, 0.f, 0.f};
#pragma unroll
  for (int t = 0; t < 4; ++t) o[t] = z;
  lacc = z;

  const int swl = l16 & 7;   // K/V read-side swizzle key
  const int lim = wave * 16 + l16;   // causal limit (key-in-tile) for own queries

  // prologue: stage key-tile 0 into buffer 0
  async_copy16(pKsrc, &sK[0][lo]);
  async_copy16(pKsrc + (size_t)16 * LDQKV, &sK[0][lo + 8 * 64]);
  async_copy16(pVsrc, &sV[0][lo]);
  async_copy16(pVsrc + (size_t)8 * SEQ, &sV[0][lo + 8 * 64]);

  for (int t0 = 0; t0 <= qb; ++t0) {
    const int cur = t0 & 1, nxt = cur ^ 1;
    __syncthreads();                 // tile t0 staged; prev reads of nxt done
    if (t0 < qb) {
      const size_t koff = (size_t)(t0 + 1) * 64;
      async_copy16(pKsrc + koff * LDQKV, &sK[nxt][lo]);
      async_copy16(pKsrc + (koff + 16) * LDQKV, &sK[nxt][lo + 8 * 64]);
      async_copy16(pVsrc + koff, &sV[nxt][lo]);
      async_copy16(pVsrc + (size_t)8 * SEQ + koff, &sV[nxt][lo + 8 * 64]);
    }
    const __bf16* K_ = &sK[cur][0];
    const __bf16* V_ = &sV[cur][0];

    // S^T = K Q^T : 4 row-tiles of 16 (pi-permuted) keys; after pi, lane
    // holds keys quad*8+e (sacc[0..1]) and 32+quad*8+e (sacc[2..3]) for
    // query l16.
    f32x4 sacc[4];
    __builtin_amdgcn_s_setprio(1);
#pragma unroll
    for (int ct = 0; ct < 4; ++ct) {
      bf16x8 k0 = *(const bf16x8*)(K_ + (ct * 16 + l16) * 64 + ((quad ^ swl) * 8));
      bf16x8 k1 = *(const bf16x8*)(K_ + (ct * 16 + l16) * 64 + (((4 + quad) ^ swl) * 8));
      sacc[ct] = MFMA_BF16(k0, qf[0], z);
      sacc[ct] = MFMA_BF16(k1, qf[1], sacc[ct]);
    }
    __builtin_amdgcn_s_setprio(0);

    // P = exp2(S^T), built directly in A-fragment order (no LDS round-trip):
    // ap0 element e = key quad*8+e, ap1 element e = key 32+quad*8+e.
    bf16x8 ap0, ap1;
    if (t0 < qb) {
#pragma unroll
      for (int e = 0; e < 4; ++e) {
        ap0[e]     = (__bf16)fast_exp2(sacc[0][e]);
        ap0[4 + e] = (__bf16)fast_exp2(sacc[1][e]);
        ap1[e]     = (__bf16)fast_exp2(sacc[2][e]);
        ap1[4 + e] = (__bf16)fast_exp2(sacc[3][e]);
      }
    } else {
#pragma unroll
      for (int e = 0; e < 4; ++e) {
        const int k0i = quad * 8 + e;          // ap0 low keys
        const int k1i = quad * 8 + 4 + e;      // ap0 high keys
        ap0[e]     = (__bf16)fast_exp2(k0i      <= lim ? sacc[0][e] : -1e30f);
        ap0[4 + e] = (__bf16)fast_exp2(k1i      <= lim ? sacc[1][e] : -1e30f);
        ap1[e]     = (__bf16)fast_exp2(32 + k0i <= lim ? sacc[2][e] : -1e30f);
        ap1[4 + e] = (__bf16)fast_exp2(32 + k1i <= lim ? sacc[3][e] : -1e30f);
      }
    }

    __builtin_amdgcn_s_setprio(1);
    // l += P * 1 (row sums in C-layout: row quad*4+r = query — no shuffles)
    lacc = MFMA_BF16(ap0, ones, lacc);
    lacc = MFMA_BF16(ap1, ones, lacc);

    // O += P V : 4 dk-tiles
#pragma unroll
    for (int dt = 0; dt < 4; ++dt) {
      bf16x8 v0 = *(const bf16x8*)(V_ + (dt * 16 + l16) * 64 + ((quad ^ swl) * 8));
      bf16x8 v1 = *(const bf16x8*)(V_ + (dt * 16 + l16) * 64 + (((4 + quad) ^ swl) * 8));
      o[dt] = MFMA_BF16(ap0, v0, o[dt]);
      o[dt] = MFMA_BF16(ap1, v1, o[dt]);
    }
    __builtin_amdgcn_s_setprio(0);
  }

  float linv[4];
#pragma unroll
  for (int r = 0; r < 4; ++r) linv[r] = 1.0f / lacc[r];

#pragma unroll
  for (int dt = 0; dt < 4; ++dt)
#pragma unroll
    for (int r = 0; r < 4; ++r)
      attn[(tokbase + qw + quad * 4 + r) * DMODEL + h * DKH + dt * 16 + l16] =
          (__bf16)(o[dt][r] * linv[r]);
}

// ---------------- launch ------------------------------------------------------
extern "C" void kernel_launch(void* const* d_in, const int* in_sizes, int n_in,
                              void* d_out, int out_size, void* d_ws, size_t ws_size,
                              hipStream_t stream) {
  const float* x  = (const float*)d_in[0];
  const float* wq = (const float*)d_in[1];
  const float* bq = (const float*)d_in[2];
  const float* wk = (const float*)d_in[3];
  const float* bk = (const float*)d_in[4];
  const float* wv = (const float*)d_in[5];
  const float* bv = (const float*)d_in[6];
  const float* wo = (const float*)d_in[7];
  const float* bo = (const float*)d_in[8];

  char* ws = (char*)d_ws;
  __bf16* xb    = (__bf16*)(ws + 0);
  __bf16* wqkv  = (__bf16*)(ws + 8388608);
  __bf16* wob   = (__bf16*)(ws + 14680064);
  float*  bcat  = (float*)(ws + 16777216);
  __bf16* qkv   = (__bf16*)(ws + 16789504);
  __bf16* vt    = (__bf16*)(ws + 41955328);
  __bf16* attn  = (__bf16*)(ws + 50343936);
  float*  out   = (float*)d_out;

  pack_kernel<<<1024, 256, 0, stream>>>(
      (const float4*)x, (const float4*)wq, (const float4*)wk, (const float4*)wv,
      (const float4*)wo, (const float4*)bq, (const float4*)bk, (const float4*)bv,
      (bf16x4*)xb, (bf16x4*)wqkv, (bf16x4*)wob, (float4*)bcat);

  // fused QKV projection: M=4096, N=3072, K=1024, 256x192 phase-split kernel
  // (256 blocks = exactly 1/CU, XCD-chunked). V columns written transposed
  // straight to vt — vtrans kernel deleted.
  gemm_qkv_256x192<<<256, 512, 0, stream>>>(xb, wqkv, bcat, qkv, vt);

  // flash attention: 1-D grid, balanced swizzle, in-register P (pi-permuted K)
  attn_kernel<<<1024, 256, 0, stream>>>(qkv, vt, attn);

  // output projection: M=4096, N=1024, K=1024, 128x128 phase-split kernel
  // (256 blocks = exactly 1/CU, XCD-chunked)
  gemm_out_128<<<256, 512, 0, stream>>>(attn, wob, bo, out);
}

// Round 12
// 165.726 us; speedup vs baseline: 1.0142x; 1.0142x over previous
//
#include <hip/hip_runtime.h>
#include <cstdint>

// Problem constants: B=2, L=2048, D=1024, H=16, DK=64
#define SEQ     2048
#define DMODEL  1024
#define NHEAD   16
#define DKH     64
#define NTOK    4096      // B*L
#define LDQKV   3072      // qkv buffer row stride (q|k|v)

typedef __bf16 bf16x8 __attribute__((ext_vector_type(8)));
typedef __bf16 bf16x4 __attribute__((ext_vector_type(4)));
typedef float  f32x4  __attribute__((ext_vector_type(4)));

#define MFMA_BF16(a, b, c) __builtin_amdgcn_mfma_f32_16x16x32_bf16((a), (b), (c), 0, 0, 0)

// 0.125 * log2(e): folded into wq/bq at pack time. Softmax shift dropped
// entirely — exp2(s) scales O and l identically, cancels in O/l.
#define C2F 0.18033688f

__device__ inline float fast_exp2(float x) {
#if __has_builtin(__builtin_amdgcn_exp2f)
  return __builtin_amdgcn_exp2f(x);
#else
  return __expf(x * 0.69314718056f);
#endif
}

// async global->LDS copy, 16B per lane; LDS dest is wave-uniform base + lane*16
__device__ inline void async_copy16(const void* g, void* l) {
  __builtin_amdgcn_global_load_lds(
      reinterpret_cast<const __attribute__((address_space(1))) void*>(
          reinterpret_cast<uintptr_t>(g)),
      reinterpret_cast<__attribute__((address_space(3))) void*>(
          reinterpret_cast<uintptr_t>(l)),
      16, 0, 0);
}

__device__ inline bf16x4 cvt4(float4 v) {
  bf16x4 r;
  r[0] = (__bf16)v.x; r[1] = (__bf16)v.y; r[2] = (__bf16)v.z; r[3] = (__bf16)v.w;
  return r;
}

// ---------------- pack: fp32 -> bf16 casts + weight/bias concat ----------------
__global__ __launch_bounds__(256) void pack_kernel(
    const float4* __restrict__ x,
    const float4* __restrict__ wq, const float4* __restrict__ wk,
    const float4* __restrict__ wv, const float4* __restrict__ wo,
    const float4* __restrict__ bq, const float4* __restrict__ bk,
    const float4* __restrict__ bv,
    bf16x4* __restrict__ xb, bf16x4* __restrict__ wqkv,
    bf16x4* __restrict__ wob, float4* __restrict__ bcat)
{
  const int NX = NTOK * DMODEL / 4;       // 1048576 float4 groups of x
  const int NW = DMODEL * DMODEL / 4;     // 262144 per weight
  const int TOT = NX + 4 * NW + 3 * (DMODEL / 4);
  for (int g = blockIdx.x * 256 + threadIdx.x; g < TOT; g += gridDim.x * 256) {
    if (g < NX) {
      xb[g] = cvt4(x[g]);
    } else if (g < NX + 3 * NW) {
      int g2 = g - NX;
      const float4* s = (g2 < NW) ? wq : (g2 < 2 * NW ? wk : wv);
      float4 v = s[g2 & (NW - 1)];
      if (g2 < NW) { v.x *= C2F; v.y *= C2F; v.z *= C2F; v.w *= C2F; }
      wqkv[g2] = cvt4(v);
    } else if (g < NX + 4 * NW) {
      int g3 = g - NX - 3 * NW;
      wob[g3] = cvt4(wo[g3]);
    } else {
      int g4 = g - NX - 4 * NW;
      const float4* s = (g4 < 256) ? bq : (g4 < 512 ? bk : bv);
      float4 v = s[g4 & 255];
      if (g4 < 256) { v.x *= C2F; v.y *= C2F; v.z *= C2F; v.w *= C2F; }
      bcat[g4] = v;
    }
  }
}

// ---------------- QKV GEMM, 256x192 tile, BK=64, 8 waves, phase-split ---------
// (r7 verified: 256 blocks = exactly 1/CU, XCD-chunked. Frozen. r11's fused
// transposed-V epilogue REVERTED: its 8B stores at 4KB stride fragmented
// writes (16 lines/instr) and cost more than the vtrans dispatch it saved.)
__global__ __launch_bounds__(512, 2) void gemm_qkv_256x192(
    const __bf16* __restrict__ A,    // xb  [4096][1024]
    const __bf16* __restrict__ W,    // wqkv [3072][1024]
    const float* __restrict__ bias,  // bcat [3072]
    __bf16* __restrict__ C)          // qkv [4096][3072]
{
  constexpr int K = 1024;
  __shared__ __bf16 sA[2][256 * 64];  // 32KB each
  __shared__ __bf16 sB[2][192 * 64];  // 24KB each
  const int tid  = threadIdx.x;
  const int wave = tid >> 6, lane = tid & 63;
  const int quad = lane >> 4, l16 = lane & 15;
  const int wm = wave >> 2, wn = wave & 3;     // 2 x 4 wave grid
  const int swl = l16 & 7;
  const int bid = blockIdx.x;
  const int xcd = bid & 7, slot = bid >> 3;
  const int mt = (xcd >> 1) * 4 + (slot >> 3);   // 0..15
  const int nt = (xcd & 1) * 8 + (slot & 7);     // 0..15
  const size_t m0 = (size_t)mt * 256;
  const size_t n0 = (size_t)nt * 192;

  // staging bases: lane -> (row = chunk*8 + lane>>3, LDS granule lane&7,
  // source granule pre-swizzled by row&7)
  const int srow = lane >> 3;
  const int sgr  = (lane & 7) ^ srow;
  const __bf16* pA = A + (m0 + srow) * K + sgr * 8;
  const __bf16* pB = W + (n0 + srow) * K + sgr * 8;

  f32x4 acc[8][3];
  const f32x4 z = {0.f, 0.f, 0.f, 0.f};
#pragma unroll
  for (int i = 0; i < 8; ++i)
#pragma unroll
    for (int j = 0; j < 3; ++j) acc[i][j] = z;

#define STAGE_QKV(buf, k0)                                                    \
  {                                                                           \
    _Pragma("unroll")                                                         \
    for (int L = 0; L < 4; ++L) {          /* A: 32 chunks of 8 rows */       \
      const int c = L * 8 + wave;                                             \
      async_copy16(pA + (size_t)(c * 8) * K + (k0), &sA[buf][c * 512]);       \
    }                                                                         \
    _Pragma("unroll")                                                         \
    for (int L = 0; L < 3; ++L) {          /* B: 24 chunks of 8 rows */       \
      const int c = L * 8 + wave;                                             \
      async_copy16(pB + (size_t)(c * 8) * K + (k0), &sB[buf][c * 512]);       \
    }                                                                         \
  }

  int cur = 0;
  STAGE_QKV(0, 0);
  __syncthreads();                   // vmcnt(0) drain: tile 0 landed

  for (int t = 0; t < 16; ++t) {
    const __bf16* A_ = &sA[cur][0];
    const __bf16* B_ = &sB[cur][0];
    if (t + 1 < 16) STAGE_QKV(cur ^ 1, (t + 1) * 64);   // earliest issue

    bf16x8 af[4][2], bw[3][2];
    // ---- phase 1: B cols (all 3 j) + A rows 0..63 of wave; acc[0..3][*]
#pragma unroll
    for (int j = 0; j < 3; ++j) {
      const __bf16* r = B_ + (wn * 48 + j * 16 + l16) * 64;
      bw[j][0] = *(const bf16x8*)(r + ((quad ^ swl) * 8));
      bw[j][1] = *(const bf16x8*)(r + (((4 + quad) ^ swl) * 8));
    }
#pragma unroll
    for (int i = 0; i < 4; ++i) {
      const __bf16* r = A_ + (wm * 128 + i * 16 + l16) * 64;
      af[i][0] = *(const bf16x8*)(r + ((quad ^ swl) * 8));
      af[i][1] = *(const bf16x8*)(r + (((4 + quad) ^ swl) * 8));
    }
    __builtin_amdgcn_s_setprio(1);
#pragma unroll
    for (int i = 0; i < 4; ++i)
#pragma unroll
      for (int j = 0; j < 3; ++j) {
        acc[i][j] = MFMA_BF16(af[i][0], bw[j][0], acc[i][j]);
        acc[i][j] = MFMA_BF16(af[i][1], bw[j][1], acc[i][j]);
      }
    __builtin_amdgcn_s_setprio(0);
    __builtin_amdgcn_s_barrier();

    // ---- phase 2: A rows 64..127 (overwrite af); acc[4..7][*]; boundary
#pragma unroll
    for (int i = 0; i < 4; ++i) {
      const __bf16* r = A_ + (wm * 128 + 64 + i * 16 + l16) * 64;
      af[i][0] = *(const bf16x8*)(r + ((quad ^ swl) * 8));
      af[i][1] = *(const bf16x8*)(r + (((4 + quad) ^ swl) * 8));
    }
    __builtin_amdgcn_s_setprio(1);
#pragma unroll
    for (int i = 0; i < 4; ++i)
#pragma unroll
      for (int j = 0; j < 3; ++j) {
        acc[4 + i][j] = MFMA_BF16(af[i][0], bw[j][0], acc[4 + i][j]);
        acc[4 + i][j] = MFMA_BF16(af[i][1], bw[j][1], acc[4 + i][j]);
      }
    __builtin_amdgcn_s_setprio(0);
    asm volatile("s_waitcnt vmcnt(0)" ::: "memory");  // next tile landed
    __builtin_amdgcn_s_barrier();
    cur ^= 1;
  }
#undef STAGE_QKV

  float bi[3];
#pragma unroll
  for (int j = 0; j < 3; ++j) bi[j] = bias[n0 + wn * 48 + j * 16 + l16];

#pragma unroll
  for (int i = 0; i < 8; ++i)
#pragma unroll
    for (int j = 0; j < 3; ++j)
#pragma unroll
      for (int r = 0; r < 4; ++r) {
        size_t row = m0 + wm * 128 + i * 16 + quad * 4 + r;
        size_t col = n0 + wn * 48 + j * 16 + l16;
        C[row * LDQKV + col] = (__bf16)(acc[i][j][r] + bi[j]);
      }
}

// ---------------- out-proj GEMM, 128x128 tile, BK=64, 8 waves -----------------
// (r8 verified: 256 blocks = exactly 1/CU, XCD-chunked. Frozen.)
__global__ __launch_bounds__(512, 2) void gemm_out_128(
    const __bf16* __restrict__ A,    // attn [4096][1024]
    const __bf16* __restrict__ W,    // wob  [1024][1024]
    const float* __restrict__ bias,  // bo   [1024]
    float* __restrict__ C)           // out  [4096][1024]
{
  constexpr int K = 1024;
  __shared__ __bf16 sA[2][128 * 64];  // 16KB each
  __shared__ __bf16 sB[2][128 * 64];
  const int tid  = threadIdx.x;
  const int wave = tid >> 6, lane = tid & 63;
  const int quad = lane >> 4, l16 = lane & 15;
  const int wm = wave >> 2, wn = wave & 3;     // 2 x 4 wave grid
  const int swl = l16 & 7;
  const int bid = blockIdx.x;
  const int xcd = bid & 7, slot = bid >> 3;    // slot 0..31
  const int mt = xcd * 4 + (slot >> 3);        // 0..31
  const int nt = slot & 7;                     // 0..7
  const size_t m0 = (size_t)mt * 128;
  const size_t n0 = (size_t)nt * 128;

  const int srow = lane >> 3;
  const int sgr  = (lane & 7) ^ srow;
  const __bf16* pA = A + (m0 + srow) * K + sgr * 8;
  const __bf16* pB = W + (n0 + srow) * K + sgr * 8;

  f32x4 acc[4][2];
  const f32x4 z = {0.f, 0.f, 0.f, 0.f};
#pragma unroll
  for (int i = 0; i < 4; ++i)
#pragma unroll
    for (int j = 0; j < 2; ++j) acc[i][j] = z;

#define STAGE_OUT(buf, k0)                                                    \
  {                                                                           \
    _Pragma("unroll")                                                         \
    for (int L = 0; L < 2; ++L) {          /* 16 chunks of 8 rows each */     \
      const int c = L * 8 + wave;                                             \
      async_copy16(pA + (size_t)(c * 8) * K + (k0), &sA[buf][c * 512]);       \
      async_copy16(pB + (size_t)(c * 8) * K + (k0), &sB[buf][c * 512]);       \
    }                                                                         \
  }

  int cur = 0;
  STAGE_OUT(0, 0);
  __syncthreads();                   // vmcnt(0) drain: tile 0 landed

  for (int t = 0; t < 16; ++t) {
    const __bf16* A_ = &sA[cur][0];
    const __bf16* B_ = &sB[cur][0];
    if (t + 1 < 16) STAGE_OUT(cur ^ 1, (t + 1) * 64);   // earliest issue

    bf16x8 af[4][2], bw[2][2];
#pragma unroll
    for (int j = 0; j < 2; ++j) {
      const __bf16* r = B_ + (wn * 32 + j * 16 + l16) * 64;
      bw[j][0] = *(const bf16x8*)(r + ((quad ^ swl) * 8));
      bw[j][1] = *(const bf16x8*)(r + (((4 + quad) ^ swl) * 8));
    }
#pragma unroll
    for (int i = 0; i < 4; ++i) {
      const __bf16* r = A_ + (wm * 64 + i * 16 + l16) * 64;
      af[i][0] = *(const bf16x8*)(r + ((quad ^ swl) * 8));
      af[i][1] = *(const bf16x8*)(r + (((4 + quad) ^ swl) * 8));
    }
    __builtin_amdgcn_s_setprio(1);
#pragma unroll
    for (int i = 0; i < 4; ++i)
#pragma unroll
      for (int j = 0; j < 2; ++j) {
        acc[i][j] = MFMA_BF16(af[i][0], bw[j][0], acc[i][j]);
        acc[i][j] = MFMA_BF16(af[i][1], bw[j][1], acc[i][j]);
      }
    __builtin_amdgcn_s_setprio(0);
    asm volatile("s_waitcnt vmcnt(0)" ::: "memory");  // next tile landed
    __builtin_amdgcn_s_barrier();    // all reads of cur done; nxt complete
    cur ^= 1;
  }
#undef STAGE_OUT

  float bi[2];
#pragma unroll
  for (int j = 0; j < 2; ++j) bi[j] = bias[n0 + wn * 32 + j * 16 + l16];

#pragma unroll
  for (int i = 0; i < 4; ++i)
#pragma unroll
    for (int j = 0; j < 2; ++j)
#pragma unroll
      for (int r = 0; r < 4; ++r) {
        size_t row = m0 + wm * 64 + i * 16 + quad * 4 + r;
        size_t col = n0 + wn * 32 + j * 16 + l16;
        C[row * DMODEL + col] = acc[i][j][r] + bi[j];
      }
}

// ---------------- V transpose: qkv v-slice (n, d) -> vt[(b,h,dk)][l] ----------
// (r9: vectorized bf16x8 both sides, granule-XOR LDS transpose. Frozen.)
__global__ __launch_bounds__(256) void vtrans_kernel(
    const __bf16* __restrict__ qkv, __bf16* __restrict__ vt)
{
  __shared__ __bf16 t[64 * 64];        // 8KB
  const int tid = threadIdx.x;
  const int bh = blockIdx.x;           // b*16+h
  const int b = bh >> 4, h = bh & 15;
  const int l0 = blockIdx.y * 64;
  const size_t tokbase = (size_t)b * SEQ;

  // read: 512 chunks of 8 bf16; thread handles chunks tid and tid+256
#pragma unroll
  for (int p = 0; p < 2; ++p) {
    const int chunk = p * 256 + tid;
    const int row = chunk >> 3;        // token within tile
    const int gr  = chunk & 7;         // dk granule
    bf16x8 v = *(const bf16x8*)(
        qkv + (tokbase + l0 + row) * LDQKV + 2048 + h * DKH + gr * 8);
    const int g2 = gr ^ (row & 7) ^ (row >> 3);
    *(bf16x8*)(t + row * 64 + g2 * 8) = v;
  }
  __syncthreads();

  // write: 512 chunks; chunk -> (dk = chunk>>3, token group gc = chunk&7)
#pragma unroll
  for (int p = 0; p < 2; ++p) {
    const int chunk = p * 256 + tid;
    const int dk = chunk >> 3;
    const int gc = chunk & 7;
    bf16x8 o;
#pragma unroll
    for (int k = 0; k < 8; ++k) {
      const int row = gc * 8 + k;      // row&7 == k, row>>3 == gc
      const int g = (dk >> 3) ^ k ^ gc;
      o[k] = t[row * 64 + g * 8 + (dk & 7)];
    }
    *(bf16x8*)(vt + ((size_t)bh * DKH + dk) * SEQ + l0 + gc * 8) = o;
  }
}

// ---------------- MFMA flash attention (causal) -------------------------------
// (r10 verified: in-register P via pi-permuted K staging; bit-identical to
// the r3 pbuf path with the LDS round-trip deleted. Frozen.)
__global__ __launch_bounds__(256) void attn_kernel(
    const __bf16* __restrict__ qkv,   // [4096][3072]
    const __bf16* __restrict__ vt,    // [32*64][2048]
    __bf16* __restrict__ attn)        // [4096][1024]
{
  __shared__ __bf16 sK[2][64 * 64];   // [key pi-permuted][dk], granule-swizzled
  __shared__ __bf16 sV[2][64 * 64];   // [dk][key], granule-swizzled
  const int tid  = threadIdx.x;
  const int wave = tid >> 6, lane = tid & 63;
  const int quad = lane >> 4, l16 = lane & 15;
  const int id = blockIdx.x;
  const int u = (id >> 3) & 31, v = id & 7, w = id >> 8;
  const int bh = v * 4 + w;
  const int ue = u ^ ((w >> 1) << 3);         // temporal mix across the CU's 4 blocks
  const int qb = (w & 1) ? ue : 31 - ue;
  const int b = bh >> 4, h = bh & 15;
  const int q0 = qb * 64;
  const int qw = q0 + wave * 16;              // wave's first query row
  const size_t tokbase = (size_t)b * SEQ;

  // staging: lane l -> (LDS row = l>>3, swizzled granule (l&7)^(l>>3))
  const int srow = lane >> 3;
  const int sgr  = (lane & 7) ^ srow;
  // K source row for LDS row (wave*16 + instr*8 + srow) under pi:
  //   krow = (wave>>1)*32 + (wave&1)*4 + (lane>>5)*8 + ((lane>>3)&3)
  //   instr 0 -> +0 rows, instr 1 -> +16 rows
  const int krow = (wave >> 1) * 32 + (wave & 1) * 4 + (lane >> 5) * 8 + (srow & 3);
  const __bf16* pKsrc = qkv + (tokbase + krow) * LDQKV + 1024 + h * DKH + sgr * 8;
  const __bf16* pVsrc = vt + ((size_t)bh * DKH + wave * 16 + srow) * SEQ + sgr * 8;
  const int lo = wave * 16 * 64;              // wave's slab within buffer

  bf16x8 qf[2];
#pragma unroll
  for (int s = 0; s < 2; ++s)
    qf[s] = *(const bf16x8*)(qkv + (tokbase + qw + l16) * LDQKV + h * DKH + s * 32 + quad * 8);

  bf16x8 ones;
#pragma unroll
  for (int i = 0; i < 8; ++i) ones[i] = (__bf16)1.0f;

  f32x4 o[4], lacc;
  const f32x4 z = {0.f, 0.f, 0.f, 0.f};
#pragma unroll
  for (int t = 0; t < 4; ++t) o[t] = z;
  lacc = z;

  const int swl = l16 & 7;   // K/V read-side swizzle key
  const int lim = wave * 16 + l16;   // causal limit (key-in-tile) for own queries

  // prologue: stage key-tile 0 into buffer 0
  async_copy16(pKsrc, &sK[0][lo]);
  async_copy16(pKsrc + (size_t)16 * LDQKV, &sK[0][lo + 8 * 64]);
  async_copy16(pVsrc, &sV[0][lo]);
  async_copy16(pVsrc + (size_t)8 * SEQ, &sV[0][lo + 8 * 64]);

  for (int t0 = 0; t0 <= qb; ++t0) {
    const int cur = t0 & 1, nxt = cur ^ 1;
    __syncthreads();                 // tile t0 staged; prev reads of nxt done
    if (t0 < qb) {
      const size_t koff = (size_t)(t0 + 1) * 64;
      async_copy16(pKsrc + koff * LDQKV, &sK[nxt][lo]);
      async_copy16(pKsrc + (koff + 16) * LDQKV, &sK[nxt][lo + 8 * 64]);
      async_copy16(pVsrc + koff, &sV[nxt][lo]);
      async_copy16(pVsrc + (size_t)8 * SEQ + koff, &sV[nxt][lo + 8 * 64]);
    }
    const __bf16* K_ = &sK[cur][0];
    const __bf16* V_ = &sV[cur][0];

    // S^T = K Q^T : 4 row-tiles of 16 (pi-permuted) keys; after pi, lane
    // holds keys quad*8+e (sacc[0..1]) and 32+quad*8+e (sacc[2..3]) for
    // query l16.
    f32x4 sacc[4];
    __builtin_amdgcn_s_setprio(1);
#pragma unroll
    for (int ct = 0; ct < 4; ++ct) {
      bf16x8 k0 = *(const bf16x8*)(K_ + (ct * 16 + l16) * 64 + ((quad ^ swl) * 8));
      bf16x8 k1 = *(const bf16x8*)(K_ + (ct * 16 + l16) * 64 + (((4 + quad) ^ swl) * 8));
      sacc[ct] = MFMA_BF16(k0, qf[0], z);
      sacc[ct] = MFMA_BF16(k1, qf[1], sacc[ct]);
    }
    __builtin_amdgcn_s_setprio(0);

    // P = exp2(S^T), built directly in A-fragment order (no LDS round-trip):
    // ap0 element e = key quad*8+e, ap1 element e = key 32+quad*8+e.
    bf16x8 ap0, ap1;
    if (t0 < qb) {
#pragma unroll
      for (int e = 0; e < 4; ++e) {
        ap0[e]     = (__bf16)fast_exp2(sacc[0][e]);
        ap0[4 + e] = (__bf16)fast_exp2(sacc[1][e]);
        ap1[e]     = (__bf16)fast_exp2(sacc[2][e]);
        ap1[4 + e] = (__bf16)fast_exp2(sacc[3][e]);
      }
    } else {
#pragma unroll
      for (int e = 0; e < 4; ++e) {
        const int k0i = quad * 8 + e;          // ap0 low keys
        const int k1i = quad * 8 + 4 + e;      // ap0 high keys
        ap0[e]     = (__bf16)fast_exp2(k0i      <= lim ? sacc[0][e] : -1e30f);
        ap0[4 + e] = (__bf16)fast_exp2(k1i      <= lim ? sacc[1][e] : -1e30f);
        ap1[e]     = (__bf16)fast_exp2(32 + k0i <= lim ? sacc[2][e] : -1e30f);
        ap1[4 + e] = (__bf16)fast_exp2(32 + k1i <= lim ? sacc[3][e] : -1e30f);
      }
    }

    __builtin_amdgcn_s_setprio(1);
    // l += P * 1 (row sums in C-layout: row quad*4+r = query — no shuffles)
    lacc = MFMA_BF16(ap0, ones, lacc);
    lacc = MFMA_BF16(ap1, ones, lacc);

    // O += P V : 4 dk-tiles
#pragma unroll
    for (int dt = 0; dt < 4; ++dt) {
      bf16x8 v0 = *(const bf16x8*)(V_ + (dt * 16 + l16) * 64 + ((quad ^ swl) * 8));
      bf16x8 v1 = *(const bf16x8*)(V_ + (dt * 16 + l16) * 64 + (((4 + quad) ^ swl) * 8));
      o[dt] = MFMA_BF16(ap0, v0, o[dt]);
      o[dt] = MFMA_BF16(ap1, v1, o[dt]);
    }
    __builtin_amdgcn_s_setprio(0);
  }

  float linv[4];
#pragma unroll
  for (int r = 0; r < 4; ++r) linv[r] = 1.0f / lacc[r];

#pragma unroll
  for (int dt = 0; dt < 4; ++dt)
#pragma unroll
    for (int r = 0; r < 4; ++r)
      attn[(tokbase + qw + quad * 4 + r) * DMODEL + h * DKH + dt * 16 + l16] =
          (__bf16)(o[dt][r] * linv[r]);
}

// ---------------- launch ------------------------------------------------------
extern "C" void kernel_launch(void* const* d_in, const int* in_sizes, int n_in,
                              void* d_out, int out_size, void* d_ws, size_t ws_size,
                              hipStream_t stream) {
  const float* x  = (const float*)d_in[0];
  const float* wq = (const float*)d_in[1];
  const float* bq = (const float*)d_in[2];
  const float* wk = (const float*)d_in[3];
  const float* bk = (const float*)d_in[4];
  const float* wv = (const float*)d_in[5];
  const float* bv = (const float*)d_in[6];
  const float* wo = (const float*)d_in[7];
  const float* bo = (const float*)d_in[8];

  char* ws = (char*)d_ws;
  __bf16* xb    = (__bf16*)(ws + 0);
  __bf16* wqkv  = (__bf16*)(ws + 8388608);
  __bf16* wob   = (__bf16*)(ws + 14680064);
  float*  bcat  = (float*)(ws + 16777216);
  __bf16* qkv   = (__bf16*)(ws + 16789504);
  __bf16* vt    = (__bf16*)(ws + 41955328);
  __bf16* attn  = (__bf16*)(ws + 50343936);
  float*  out   = (float*)d_out;

  pack_kernel<<<1024, 256, 0, stream>>>(
      (const float4*)x, (const float4*)wq, (const float4*)wk, (const float4*)wv,
      (const float4*)wo, (const float4*)bq, (const float4*)bk, (const float4*)bv,
      (bf16x4*)xb, (bf16x4*)wqkv, (bf16x4*)wob, (float4*)bcat);

  // fused QKV projection: M=4096, N=3072, K=1024, 256x192 phase-split kernel
  // (256 blocks = exactly 1/CU, XCD-chunked)
  gemm_qkv_256x192<<<256, 512, 0, stream>>>(xb, wqkv, bcat, qkv);

  // V transpose: vectorized bf16x8 both sides, granule-XOR LDS transpose
  vtrans_kernel<<<dim3(32, 32), 256, 0, stream>>>(qkv, vt);

  // flash attention: 1-D grid, balanced swizzle, in-register P (pi-permuted K)
  attn_kernel<<<1024, 256, 0, stream>>>(qkv, vt, attn);

  // output projection: M=4096, N=1024, K=1024, 128x128 phase-split kernel
  // (256 blocks = exactly 1/CU, XCD-chunked)
  gemm_out_128<<<256, 512, 0, stream>>>(attn, wob, bo, out);
}